// Round 16
// baseline (128.662 us; speedup 1.0000x reference)
//
#include <hip/hip_runtime.h>

#define B_ 4
#define H_ 16
#define SQ 2048
#define DH 64
#define DMODEL 1024

typedef __attribute__((ext_vector_type(8))) short bf16x8;
typedef __attribute__((ext_vector_type(4))) float f32x4;

static __device__ __forceinline__ unsigned short f2bf(float f) {
  union { float f; unsigned u; } v; v.f = f;
  unsigned r = v.u + 0x7fffu + ((v.u >> 16) & 1u);
  return (unsigned short)(r >> 16);
}
static __device__ __forceinline__ float bf2f(unsigned short u) {
  union { unsigned u; float f; } v; v.u = ((unsigned)u) << 16;
  return v.f;
}
static __device__ __forceinline__ unsigned cvt_pk_bf16(float lo, float hi) {
  unsigned r;
  asm("v_cvt_pk_bf16_f32 %0, %1, %2" : "=v"(r) : "v"(lo), "v"(hi));
  return r;
}
// bare v_exp_f32: args are bounded (|x| <~ 20), skip libm's range fixups
static __device__ __forceinline__ float fast_exp2(float x) {
  float r;
  asm("v_exp_f32 %0, %1" : "=v"(r) : "v"(x));
  return r;
}

// -log2(10000)/16
#define NEG_FREQ_LOG2 (-0.8304820237218405f)
#define QSCALE (0.125f * 1.44269504088896f)  // 1/sqrt(64) * log2(e)

// sin/cos tables: [s][j] for s in [0,2048), j in [0,16)
__global__ void gen_tbl(float* __restrict__ cosT, float* __restrict__ sinT) {
  int t = blockIdx.x * 256 + threadIdx.x;
  int s = t >> 4, j = t & 15;
  float ang = (float)s * exp2f(NEG_FREQ_LOG2 * (float)j);
  cosT[t] = cosf(ang);
  sinT[t] = sinf(ang);
}

// Fragment-major prep: for each (bh, t) 64-key tile write
//   K:  elem((m*2+c)*64 + l)*8 + j  = K_roped[key = m*16+(l&15)][d = c*32+(l>>4)*8+j]
//   V^T: same formula              = V[key = c*32+(l>>4)*8+j][d = m*16+(l&15)]
__global__ __launch_bounds__(256) void prep_frag(
    const float* __restrict__ k, const float* __restrict__ v,
    unsigned short* __restrict__ kf, unsigned short* __restrict__ vf,
    const float* __restrict__ cosT, const float* __restrict__ sinT) {
  __shared__ float T[64][68];
  int bid = blockIdx.x;          // bh*32 + t
  int bh = bid >> 5;
  int b = bh >> 4, h = bh & 15;
  int tid = threadIdx.x;
  int sr = tid >> 2, sq = tid & 3;
  int s = (bid & 31) * 64 + sr;
  size_t srcb = ((size_t)b * SQ + s) * DMODEL + (size_t)h * DH + sq * 16;
  size_t obase = (size_t)bid * 4096;

  // ---- K stage (RoPE'd, f32) ----
  {
    float __align__(16) x[16];
#pragma unroll
    for (int c = 0; c < 4; ++c) *(float4*)(x + c * 4) = *(const float4*)(k + srcb + c * 4);
    if (sq < 2) {
      float __align__(16) p[16], cs[16], sn[16];
      const float* pb = k + srcb + (sq ? -16 : 16);
#pragma unroll
      for (int c = 0; c < 4; ++c) *(float4*)(p + c * 4) = *(const float4*)(pb + c * 4);
#pragma unroll
      for (int c = 0; c < 4; ++c) *(float4*)(cs + c * 4) = *(const float4*)(cosT + s * 16 + c * 4);
#pragma unroll
      for (int c = 0; c < 4; ++c) *(float4*)(sn + c * 4) = *(const float4*)(sinT + s * 16 + c * 4);
      float sgn = sq ? 1.f : -1.f;
#pragma unroll
      for (int j = 0; j < 16; ++j) x[j] = x[j] * cs[j] + sgn * p[j] * sn[j];
    }
#pragma unroll
    for (int c = 0; c < 4; ++c) *(float4*)&T[sr][sq * 16 + c * 4] = *(float4*)(x + c * 4);
  }
  __syncthreads();
  // ---- K readout (fragment-major) ----
#pragma unroll
  for (int r = 0; r < 2; ++r) {
    int slot = tid + r * 256;
    int m = slot >> 7, c = (slot >> 6) & 1, l = slot & 63;
    int row = m * 16 + (l & 15), d0 = c * 32 + ((l >> 4) & 3) * 8;
    float4 a = *(float4*)&T[row][d0];
    float4 b2 = *(float4*)&T[row][d0 + 4];
    unsigned short __align__(16) o[8];
    o[0] = f2bf(a.x); o[1] = f2bf(a.y); o[2] = f2bf(a.z); o[3] = f2bf(a.w);
    o[4] = f2bf(b2.x); o[5] = f2bf(b2.y); o[6] = f2bf(b2.z); o[7] = f2bf(b2.w);
    *(uint4*)(kf + obase + slot * 8) = *(uint4*)o;
  }
  __syncthreads();
  // ---- V stage (raw f32) ----
  {
    float __align__(16) x[16];
#pragma unroll
    for (int c = 0; c < 4; ++c) *(float4*)(x + c * 4) = *(const float4*)(v + srcb + c * 4);
#pragma unroll
    for (int c = 0; c < 4; ++c) *(float4*)&T[sr][sq * 16 + c * 4] = *(float4*)(x + c * 4);
  }
  __syncthreads();
  // ---- V^T readout (fragment-major) ----
#pragma unroll
  for (int r = 0; r < 2; ++r) {
    int slot = tid + r * 256;
    int m = slot >> 7, c = (slot >> 6) & 1, l = slot & 63;
    int d = m * 16 + (l & 15), key0 = c * 32 + ((l >> 4) & 3) * 8;
    unsigned short __align__(16) o[8];
#pragma unroll
    for (int j = 0; j < 8; ++j) o[j] = f2bf(T[key0 + j][d]);
    *(uint4*)(vf + obase + slot * 8) = *(uint4*)o;
  }
}

// Flash attention, LDS-free streaming, qg=2, grid 1024 (round-15 structure)
// + K-fragment DOUBLE BUFFER: next tile's K loads issue before this tile's
// compute, so the tile-boundary K-load latency hides under QK/exp/PV.
// V stays on-demand (latency covered by exp/pack; 2nd qg hits L1).
__global__ __launch_bounds__(256) void attn15(
    const float* __restrict__ q, const float* __restrict__ kreg,
    const float* __restrict__ vreg,
    const unsigned short* __restrict__ kf, const unsigned short* __restrict__ vf,
    const float* __restrict__ cosT, const float* __restrict__ sinT,
    float* __restrict__ out) {
  int bid = blockIdx.x;  // 1024 = 8 xcd x (8 bh x 16 qt)
  int xcd = bid & 7, jj = bid >> 3;
  int bh = xcd * 8 + (jj >> 4);
  int qt = jj & 15;
  int b = bh >> 4, h = bh & 15;
  int tid = threadIdx.x, w = tid >> 6, l = tid & 63, g = l >> 4, lc = l & 15;

  const unsigned short* kt = kf + (size_t)bh * 32 * 4096 + l * 8;
  const unsigned short* vt = vf + (size_t)bh * 32 * 4096 + l * 8;

  // ---- Q fragments (RoPE + QSCALE), 2 q-groups ----
  bf16x8 aQ0[2], aQ1[2];
#pragma unroll
  for (int qg = 0; qg < 2; ++qg) {
    int qrow = qt * 128 + w * 32 + qg * 16 + lc;
    const float* qb = q + ((size_t)b * SQ + qrow) * DMODEL + (size_t)h * DH;
    int d0 = g * 8;
    float __align__(16) x[8], p[8], cs[8], sn[8];
    *(float4*)(x) = *(const float4*)(qb + d0);
    *(float4*)(x + 4) = *(const float4*)(qb + d0 + 4);
    *(float4*)(p) = *(const float4*)(qb + (d0 ^ 16));
    *(float4*)(p + 4) = *(const float4*)(qb + (d0 ^ 16) + 4);
    const float* cb = cosT + qrow * 16 + (g & 1) * 8;
    const float* sb = sinT + qrow * 16 + (g & 1) * 8;
    *(float4*)(cs) = *(const float4*)(cb);
    *(float4*)(cs + 4) = *(const float4*)(cb + 4);
    *(float4*)(sn) = *(const float4*)(sb);
    *(float4*)(sn + 4) = *(const float4*)(sb + 4);
    float sgn = (d0 < 16) ? -1.f : 1.f;
    unsigned short __align__(16) t0[8];
#pragma unroll
    for (int j = 0; j < 8; ++j) t0[j] = f2bf((x[j] * cs[j] + sgn * p[j] * sn[j]) * QSCALE);
    aQ0[qg] = *(bf16x8*)t0;
    *(float4*)(x) = *(const float4*)(qb + 32 + d0);
    *(float4*)(x + 4) = *(const float4*)(qb + 32 + d0 + 4);
#pragma unroll
    for (int j = 0; j < 8; ++j) t0[j] = f2bf(x[j] * QSCALE);
    aQ1[qg] = *(bf16x8*)t0;
  }

  f32x4 oacc[2][4];
  f32x4 lacc[2];
#pragma unroll
  for (int qg = 0; qg < 2; ++qg) {
#pragma unroll
    for (int m = 0; m < 4; ++m) oacc[qg][m] = (f32x4){0.f, 0.f, 0.f, 0.f};
    lacc[qg] = (f32x4){0.f, 0.f, 0.f, 0.f};
  }
  // ones A-fragment (bf16 1.0 = 0x3F80) for l-sum MFMA
  union { unsigned u[4]; bf16x8 v8; } onesf;
#pragma unroll
  for (int i = 0; i < 4; ++i) onesf.u[i] = 0x3F803F80u;

// ---- load tile T's K fragments into named register set KD ----
#define LOADK(KD, T) do { \
  const unsigned short* Kp_ = kt + (size_t)(T) * 4096; \
  _Pragma("unroll") \
  for (int i_ = 0; i_ < 8; ++i_) KD[i_] = *(const bf16x8*)(Kp_ + i_ * 512); \
} while (0)

// ---- full tile compute against K set KD, V streamed on-demand for tile T ----
#define COMPUTE(KD, T) do { \
  const unsigned short* Vp_ = vt + (size_t)(T) * 4096; \
  _Pragma("unroll") \
  for (int qg_ = 0; qg_ < 2; ++qg_) { \
    f32x4 sm_[4]; \
    _Pragma("unroll") \
    for (int m_ = 0; m_ < 4; ++m_) { \
      f32x4 acc_ = (f32x4){0.f, 0.f, 0.f, 0.f}; \
      acc_ = __builtin_amdgcn_mfma_f32_16x16x32_bf16(KD[2 * m_], aQ0[qg_], acc_, 0, 0, 0); \
      acc_ = __builtin_amdgcn_mfma_f32_16x16x32_bf16(KD[2 * m_ + 1], aQ1[qg_], acc_, 0, 0, 0); \
      sm_[m_] = acc_; \
    } \
    _Pragma("unroll") \
    for (int m_ = 0; m_ < 4; ++m_) \
      _Pragma("unroll") \
      for (int r_ = 0; r_ < 4; ++r_) sm_[m_][r_] = fast_exp2(sm_[m_][r_]); \
    unsigned wd_[4][2]; \
    _Pragma("unroll") \
    for (int m_ = 0; m_ < 4; ++m_) { \
      wd_[m_][0] = cvt_pk_bf16(sm_[m_][0], sm_[m_][1]); \
      wd_[m_][1] = cvt_pk_bf16(sm_[m_][2], sm_[m_][3]); \
    } \
    union { unsigned u[4]; bf16x8 v8; } f0_, f1_; \
    _Pragma("unroll") \
    for (int c_ = 0; c_ < 2; ++c_) { \
      unsigned a_ = wd_[0][c_], b_ = wd_[1][c_]; \
      asm("v_permlane32_swap_b32 %0, %1" : "+v"(a_), "+v"(b_)); \
      asm("v_permlane16_swap_b32 %0, %1" : "+v"(a_), "+v"(b_)); \
      f0_.u[c_] = a_; f0_.u[2 + c_] = b_; \
      unsigned a2_ = wd_[2][c_], b2_ = wd_[3][c_]; \
      asm("v_permlane32_swap_b32 %0, %1" : "+v"(a2_), "+v"(b2_)); \
      asm("v_permlane16_swap_b32 %0, %1" : "+v"(a2_), "+v"(b2_)); \
      f1_.u[c_] = a2_; f1_.u[2 + c_] = b2_; \
    } \
    _Pragma("unroll") \
    for (int m_ = 0; m_ < 4; ++m_) { \
      bf16x8 v0_ = *(const bf16x8*)(Vp_ + (2 * m_) * 512); \
      bf16x8 v1_ = *(const bf16x8*)(Vp_ + (2 * m_ + 1) * 512); \
      oacc[qg_][m_] = __builtin_amdgcn_mfma_f32_16x16x32_bf16(v0_, f0_.v8, oacc[qg_][m_], 0, 0, 0); \
      oacc[qg_][m_] = __builtin_amdgcn_mfma_f32_16x16x32_bf16(v1_, f1_.v8, oacc[qg_][m_], 0, 0, 0); \
    } \
    lacc[qg_] = __builtin_amdgcn_mfma_f32_16x16x32_bf16(onesf.v8, f0_.v8, lacc[qg_], 0, 0, 0); \
    lacc[qg_] = __builtin_amdgcn_mfma_f32_16x16x32_bf16(onesf.v8, f1_.v8, lacc[qg_], 0, 0, 0); \
  } \
} while (0)

  bf16x8 kA[8], kB[8];
  LOADK(kA, 0);
  for (int t = 0; t < SQ / 64; t += 2) {
    LOADK(kB, t + 1);                                   // prefetch odd tile's K
    COMPUTE(kA, t);
    int tn = (t + 2 < SQ / 64) ? t + 2 : (SQ / 64 - 1); // clamped (last redundant)
    LOADK(kA, tn);                                      // prefetch next even tile's K
    COMPUTE(kB, t + 1);
  }
#undef LOADK
#undef COMPUTE

  // ---- register K/V token + final normalize + store ----
#pragma unroll
  for (int qg = 0; qg < 2; ++qg) {
    float part = 0.f;
    const float* kb = kreg + (size_t)h * DH + 32 + g * 8;
#pragma unroll
    for (int j = 0; j < 8; ++j) part += bf2f((unsigned short)aQ1[qg][j]) * kb[j];
    part += __shfl_xor(part, 16);
    part += __shfl_xor(part, 32);
    float pr = fast_exp2(part);
    float lfin = lacc[qg][0] + pr;
    float inv = 1.f / lfin;
    int qrow = qt * 128 + w * 32 + qg * 16 + lc;
    float* ob = out + ((size_t)b * SQ + qrow) * DMODEL + (size_t)h * DH;
#pragma unroll
    for (int m = 0; m < 4; ++m) {
      float4 vv = *(const float4*)(vreg + (size_t)h * DH + m * 16 + g * 4);
      f32x4 o = oacc[qg][m];
      float4 st;
      st.x = (o[0] + pr * vv.x) * inv;
      st.y = (o[1] + pr * vv.y) * inv;
      st.z = (o[2] + pr * vv.z) * inv;
      st.w = (o[3] + pr * vv.w) * inv;
      *(float4*)(ob + m * 16 + g * 4) = st;
    }
  }
}

// ---------------- fallback (no-workspace) ----------------
__global__ __launch_bounds__(256) void attn_fallback(
    const float* __restrict__ q, const float* __restrict__ k, const float* __restrict__ v,
    const float* __restrict__ kreg, const float* __restrict__ vreg,
    float* __restrict__ out) {
  __shared__ __align__(16) unsigned short Klds[64 * 64];
  __shared__ __align__(16) unsigned short Vtlds[64 * 64];
  __shared__ __align__(16) unsigned short Plds[4][16 * 64];
  int bid = blockIdx.x;
  int xcd = bid & 7, jj = bid >> 3;
  int bh = xcd * 8 + (jj >> 5);
  int qt = jj & 31;
  int b = bh >> 4, h = bh & 15;
  int tid = threadIdx.x, w = tid >> 6, l = tid & 63, g = l >> 4, lc = l & 15;
  int qrow = qt * 64 + w * 16 + lc;
  const float* qb = q + ((size_t)b * SQ + qrow) * DMODEL + (size_t)h * DH;
  bf16x8 aQ0, aQ1;
  {
    int d0 = g * 8;
    float __align__(16) x[8], p[8];
    *(float4*)(x) = *(const float4*)(qb + d0);
    *(float4*)(x + 4) = *(const float4*)(qb + d0 + 4);
    *(float4*)(p) = *(const float4*)(qb + (d0 ^ 16));
    *(float4*)(p + 4) = *(const float4*)(qb + (d0 ^ 16) + 4);
    float sgn = (d0 < 16) ? -1.f : 1.f;
    unsigned short __align__(16) t0[8];
#pragma unroll
    for (int j = 0; j < 8; ++j) {
      int fi = (d0 + j) & 15;
      float ang = (float)qrow * exp2f(NEG_FREQ_LOG2 * (float)fi);
      t0[j] = f2bf((x[j] * cosf(ang) + sgn * p[j] * sinf(ang)) * 0.125f);
    }
    aQ0 = *(bf16x8*)t0;
    *(float4*)(x) = *(const float4*)(qb + 32 + d0);
    *(float4*)(x + 4) = *(const float4*)(qb + 32 + d0 + 4);
#pragma unroll
    for (int j = 0; j < 8; ++j) t0[j] = f2bf(x[j] * 0.125f);
    aQ1 = *(bf16x8*)t0;
  }
  f32x4 oacc[4];
#pragma unroll
  for (int n = 0; n < 4; ++n) oacc[n] = (f32x4){0.f, 0.f, 0.f, 0.f};
  float mrow[4] = {-1e30f, -1e30f, -1e30f, -1e30f};
  float lrow[4] = {0.f, 0.f, 0.f, 0.f};
  int sr = tid >> 2, sq = tid & 3;
  unsigned short* Pw = &Plds[w][0];
  for (int t = 0; t < SQ / 64; ++t) {
    int kv0 = t * 64;
    __syncthreads();
    {
      const float* kb2 = k + ((size_t)b * SQ + kv0 + sr) * DMODEL + (size_t)h * DH + sq * 16;
      float __align__(16) x[16];
#pragma unroll
      for (int c = 0; c < 4; ++c) *(float4*)(x + c * 4) = *(const float4*)(kb2 + c * 4);
      if (sq < 2) {
        const float* pb = k + ((size_t)b * SQ + kv0 + sr) * DMODEL + (size_t)h * DH + (sq ^ 1) * 16;
        float __align__(16) p[16];
#pragma unroll
        for (int c = 0; c < 4; ++c) *(float4*)(p + c * 4) = *(const float4*)(pb + c * 4);
        float sgn = sq ? 1.f : -1.f;
        float pos = (float)(kv0 + sr);
#pragma unroll
        for (int j = 0; j < 16; ++j) {
          float ang = pos * exp2f(NEG_FREQ_LOG2 * (float)j);
          x[j] = x[j] * cosf(ang) + sgn * p[j] * sinf(ang);
        }
      }
      unsigned short __align__(16) o[16];
#pragma unroll
      for (int j = 0; j < 16; ++j) o[j] = f2bf(x[j]);
      int i0 = (sr * 64 + sq * 16) ^ ((sr & 7) << 3);
      int i1 = (sr * 64 + sq * 16 + 8) ^ ((sr & 7) << 3);
      *(uint4*)&Klds[i0] = *(uint4*)o;
      *(uint4*)&Klds[i1] = *(uint4*)(o + 8);
      const float* vb = v + ((size_t)b * SQ + kv0 + sr) * DMODEL + (size_t)h * DH + sq * 16;
#pragma unroll
      for (int c = 0; c < 4; ++c) *(float4*)(x + c * 4) = *(const float4*)(vb + c * 4);
#pragma unroll
      for (int j = 0; j < 16; ++j) {
        int d = sq * 16 + j;
        Vtlds[(d * 64 + sr) ^ ((d & 7) << 3)] = f2bf(x[j]);
      }
    }
    __syncthreads();
    f32x4 sacc[4];
#pragma unroll
    for (int n = 0; n < 4; ++n) {
      int row = n * 16 + lc;
      bf16x8 b0 = *(const bf16x8*)&Klds[(row * 64 + g * 8) ^ ((row & 7) << 3)];
      bf16x8 b1 = *(const bf16x8*)&Klds[(row * 64 + 32 + g * 8) ^ ((row & 7) << 3)];
      f32x4 acc = (f32x4){0.f, 0.f, 0.f, 0.f};
      acc = __builtin_amdgcn_mfma_f32_16x16x32_bf16(aQ0, b0, acc, 0, 0, 0);
      acc = __builtin_amdgcn_mfma_f32_16x16x32_bf16(aQ1, b1, acc, 0, 0, 0);
      sacc[n] = acc;
    }
    float rmax[4];
#pragma unroll
    for (int rg = 0; rg < 4; ++rg)
      rmax[rg] = fmaxf(fmaxf(sacc[0][rg], sacc[1][rg]), fmaxf(sacc[2][rg], sacc[3][rg]));
#pragma unroll
    for (int off = 1; off < 16; off <<= 1)
#pragma unroll
      for (int rg = 0; rg < 4; ++rg) rmax[rg] = fmaxf(rmax[rg], __shfl_xor(rmax[rg], off));
    float mn[4], scl[4];
#pragma unroll
    for (int rg = 0; rg < 4; ++rg) {
      mn[rg] = fmaxf(mrow[rg], rmax[rg]);
      scl[rg] = __expf(mrow[rg] - mn[rg]);
      mrow[rg] = mn[rg];
    }
    float rsum[4] = {0.f, 0.f, 0.f, 0.f};
#pragma unroll
    for (int n = 0; n < 4; ++n)
#pragma unroll
      for (int rg = 0; rg < 4; ++rg) {
        float pe = __expf(sacc[n][rg] - mn[rg]);
        sacc[n][rg] = pe;
        rsum[rg] += pe;
      }
#pragma unroll
    for (int off = 1; off < 16; off <<= 1)
#pragma unroll
      for (int rg = 0; rg < 4; ++rg) rsum[rg] += __shfl_xor(rsum[rg], off);
    f32x4 sv;
#pragma unroll
    for (int rg = 0; rg < 4; ++rg) {
      lrow[rg] = lrow[rg] * scl[rg] + rsum[rg];
      sv[rg] = scl[rg];
    }
#pragma unroll
    for (int n = 0; n < 4; ++n) oacc[n] *= sv;
#pragma unroll
    for (int n = 0; n < 4; ++n)
#pragma unroll
      for (int rg = 0; rg < 4; ++rg) {
        int row = g * 4 + rg;
        Pw[(row * 64 + n * 16 + lc) ^ ((row & 7) << 3)] = f2bf(sacc[n][rg]);
      }
    {
      bf16x8 a0 = *(const bf16x8*)&Pw[(lc * 64 + g * 8) ^ ((lc & 7) << 3)];
      bf16x8 a1 = *(const bf16x8*)&Pw[(lc * 64 + 32 + g * 8) ^ ((lc & 7) << 3)];
#pragma unroll
      for (int n = 0; n < 4; ++n) {
        int vrow = n * 16 + lc;
        bf16x8 b0 = *(const bf16x8*)&Vtlds[(vrow * 64 + g * 8) ^ ((vrow & 7) << 3)];
        bf16x8 b1 = *(const bf16x8*)&Vtlds[(vrow * 64 + 32 + g * 8) ^ ((vrow & 7) << 3)];
        oacc[n] = __builtin_amdgcn_mfma_f32_16x16x32_bf16(a0, b0, oacc[n], 0, 0, 0);
        oacc[n] = __builtin_amdgcn_mfma_f32_16x16x32_bf16(a1, b1, oacc[n], 0, 0, 0);
      }
    }
  }
  float part = 0.f;
  {
    const float* kb = kreg + (size_t)h * DH + 32 + g * 8;
#pragma unroll
    for (int j = 0; j < 8; ++j) part += bf2f((unsigned short)aQ1[j]) * kb[j];
    part += __shfl_xor(part, 16);
    part += __shfl_xor(part, 32);
  }
  float vr[4];
#pragma unroll
  for (int n = 0; n < 4; ++n) vr[n] = vreg[(size_t)h * DH + n * 16 + lc];
#pragma unroll
  for (int rg = 0; rg < 4; ++rg) {
    float s_r = __shfl(part, g * 4 + rg);
    float mn2 = fmaxf(mrow[rg], s_r);
    float scl2 = __expf(mrow[rg] - mn2);
    float pr = __expf(s_r - mn2);
    lrow[rg] = lrow[rg] * scl2 + pr;
    float inv = 1.f / lrow[rg];
#pragma unroll
    for (int n = 0; n < 4; ++n) oacc[n][rg] = (oacc[n][rg] * scl2 + pr * vr[n]) * inv;
  }
  float* ob = out + ((size_t)b * SQ + qt * 64 + w * 16) * DMODEL + (size_t)h * DH;
#pragma unroll
  for (int rg = 0; rg < 4; ++rg) {
    int row = g * 4 + rg;
#pragma unroll
    for (int n = 0; n < 4; ++n) ob[(size_t)row * DMODEL + n * 16 + lc] = oacc[n][rg];
  }
}

extern "C" void kernel_launch(void* const* d_in, const int* in_sizes, int n_in,
                              void* d_out, int out_size, void* d_ws, size_t ws_size,
                              hipStream_t stream) {
  const float* q = (const float*)d_in[0];
  const float* k = (const float*)d_in[1];
  const float* v = (const float*)d_in[2];
  const float* kreg = (const float*)d_in[3];
  const float* vreg = (const float*)d_in[4];
  float* out = (float*)d_out;

  size_t elems = (size_t)B_ * H_ * SQ * DH;  // 8388608
  size_t tbl = (size_t)SQ * 16;
  size_t need = elems * 2ull * 2ull + tbl * 2ull * 4ull;
  if (ws_size >= need) {
    unsigned short* kf = (unsigned short*)d_ws;
    unsigned short* vf = kf + elems;
    float* cosT = (float*)(vf + elems);
    float* sinT = cosT + tbl;
    gen_tbl<<<dim3((int)(tbl / 256)), dim3(256), 0, stream>>>(cosT, sinT);
    prep_frag<<<dim3(2048), dim3(256), 0, stream>>>(k, v, kf, vf, cosT, sinT);
    attn15<<<dim3(1024), dim3(256), 0, stream>>>(q, kreg, vreg, kf, vf, cosT, sinT, out);
  } else {
    attn_fallback<<<dim3(2048), dim3(256), 0, stream>>>(q, k, v, kreg, vreg, out);
  }
}

// Round 17
// 120.915 us; speedup vs baseline: 1.0641x; 1.0641x over previous
//
#include <hip/hip_runtime.h>

#define B_ 4
#define H_ 16
#define SQ 2048
#define DH 64
#define DMODEL 1024

typedef __attribute__((ext_vector_type(8))) short bf16x8;
typedef __attribute__((ext_vector_type(4))) float f32x4;

static __device__ __forceinline__ unsigned short f2bf(float f) {
  union { float f; unsigned u; } v; v.f = f;
  unsigned r = v.u + 0x7fffu + ((v.u >> 16) & 1u);
  return (unsigned short)(r >> 16);
}
static __device__ __forceinline__ float bf2f(unsigned short u) {
  union { unsigned u; float f; } v; v.u = ((unsigned)u) << 16;
  return v.f;
}
static __device__ __forceinline__ unsigned cvt_pk_bf16(float lo, float hi) {
  unsigned r;
  asm("v_cvt_pk_bf16_f32 %0, %1, %2" : "=v"(r) : "v"(lo), "v"(hi));
  return r;
}
// bare v_exp_f32: args are bounded (|x| <~ 20), skip libm's range fixups
static __device__ __forceinline__ float fast_exp2(float x) {
  float r;
  asm("v_exp_f32 %0, %1" : "=v"(r) : "v"(x));
  return r;
}

// -log2(10000)/16
#define NEG_FREQ_LOG2 (-0.8304820237218405f)
#define QSCALE (0.125f * 1.44269504088896f)  // 1/sqrt(64) * log2(e)

// sin/cos tables: [s][j] for s in [0,2048), j in [0,16)
__global__ void gen_tbl(float* __restrict__ cosT, float* __restrict__ sinT) {
  int t = blockIdx.x * 256 + threadIdx.x;
  int s = t >> 4, j = t & 15;
  float ang = (float)s * exp2f(NEG_FREQ_LOG2 * (float)j);
  cosT[t] = cosf(ang);
  sinT[t] = sinf(ang);
}

// Fragment-major prep: for each (bh, t) 64-key tile write
//   K:  elem((m*2+c)*64 + l)*8 + j  = K_roped[key = m*16+(l&15)][d = c*32+(l>>4)*8+j]
//   V^T: same formula              = V[key = c*32+(l>>4)*8+j][d = m*16+(l&15)]
__global__ __launch_bounds__(256) void prep_frag(
    const float* __restrict__ k, const float* __restrict__ v,
    unsigned short* __restrict__ kf, unsigned short* __restrict__ vf,
    const float* __restrict__ cosT, const float* __restrict__ sinT) {
  __shared__ float T[64][68];
  int bid = blockIdx.x;          // bh*32 + t
  int bh = bid >> 5;
  int b = bh >> 4, h = bh & 15;
  int tid = threadIdx.x;
  int sr = tid >> 2, sq = tid & 3;
  int s = (bid & 31) * 64 + sr;
  size_t srcb = ((size_t)b * SQ + s) * DMODEL + (size_t)h * DH + sq * 16;
  size_t obase = (size_t)bid * 4096;

  // ---- K stage (RoPE'd, f32) ----
  {
    float __align__(16) x[16];
#pragma unroll
    for (int c = 0; c < 4; ++c) *(float4*)(x + c * 4) = *(const float4*)(k + srcb + c * 4);
    if (sq < 2) {
      float __align__(16) p[16], cs[16], sn[16];
      const float* pb = k + srcb + (sq ? -16 : 16);
#pragma unroll
      for (int c = 0; c < 4; ++c) *(float4*)(p + c * 4) = *(const float4*)(pb + c * 4);
#pragma unroll
      for (int c = 0; c < 4; ++c) *(float4*)(cs + c * 4) = *(const float4*)(cosT + s * 16 + c * 4);
#pragma unroll
      for (int c = 0; c < 4; ++c) *(float4*)(sn + c * 4) = *(const float4*)(sinT + s * 16 + c * 4);
      float sgn = sq ? 1.f : -1.f;
#pragma unroll
      for (int j = 0; j < 16; ++j) x[j] = x[j] * cs[j] + sgn * p[j] * sn[j];
    }
#pragma unroll
    for (int c = 0; c < 4; ++c) *(float4*)&T[sr][sq * 16 + c * 4] = *(float4*)(x + c * 4);
  }
  __syncthreads();
  // ---- K readout (fragment-major) ----
#pragma unroll
  for (int r = 0; r < 2; ++r) {
    int slot = tid + r * 256;
    int m = slot >> 7, c = (slot >> 6) & 1, l = slot & 63;
    int row = m * 16 + (l & 15), d0 = c * 32 + ((l >> 4) & 3) * 8;
    float4 a = *(float4*)&T[row][d0];
    float4 b2 = *(float4*)&T[row][d0 + 4];
    unsigned short __align__(16) o[8];
    o[0] = f2bf(a.x); o[1] = f2bf(a.y); o[2] = f2bf(a.z); o[3] = f2bf(a.w);
    o[4] = f2bf(b2.x); o[5] = f2bf(b2.y); o[6] = f2bf(b2.z); o[7] = f2bf(b2.w);
    *(uint4*)(kf + obase + slot * 8) = *(uint4*)o;
  }
  __syncthreads();
  // ---- V stage (raw f32) ----
  {
    float __align__(16) x[16];
#pragma unroll
    for (int c = 0; c < 4; ++c) *(float4*)(x + c * 4) = *(const float4*)(v + srcb + c * 4);
#pragma unroll
    for (int c = 0; c < 4; ++c) *(float4*)&T[sr][sq * 16 + c * 4] = *(float4*)(x + c * 4);
  }
  __syncthreads();
  // ---- V^T readout (fragment-major) ----
#pragma unroll
  for (int r = 0; r < 2; ++r) {
    int slot = tid + r * 256;
    int m = slot >> 7, c = (slot >> 6) & 1, l = slot & 63;
    int d = m * 16 + (l & 15), key0 = c * 32 + ((l >> 4) & 3) * 8;
    unsigned short __align__(16) o[8];
#pragma unroll
    for (int j = 0; j < 8; ++j) o[j] = f2bf(T[key0 + j][d]);
    *(uint4*)(vf + obase + slot * 8) = *(uint4*)o;
  }
}

// Flash attention, LDS-free streaming, qg=2, grid 1024 (round-15 structure).
// l-sum via VALU horizontal reduce (+shfl_xor 16/32) instead of ones-MFMA:
// frees 12 regs (2x f32x4 lacc + onesf) targeting the <=128 total bucket
// (4 waves/SIMD per m69). fast_exp2 softmax; K resident, V on-demand.
__global__ __launch_bounds__(256) void attn16(
    const float* __restrict__ q, const float* __restrict__ kreg,
    const float* __restrict__ vreg,
    const unsigned short* __restrict__ kf, const unsigned short* __restrict__ vf,
    const float* __restrict__ cosT, const float* __restrict__ sinT,
    float* __restrict__ out) {
  int bid = blockIdx.x;  // 1024 = 8 xcd x (8 bh x 16 qt)
  int xcd = bid & 7, jj = bid >> 3;
  int bh = xcd * 8 + (jj >> 4);
  int qt = jj & 15;
  int b = bh >> 4, h = bh & 15;
  int tid = threadIdx.x, w = tid >> 6, l = tid & 63, g = l >> 4, lc = l & 15;

  const unsigned short* kt = kf + (size_t)bh * 32 * 4096 + l * 8;
  const unsigned short* vt = vf + (size_t)bh * 32 * 4096 + l * 8;

  // ---- Q fragments (RoPE + QSCALE), 2 q-groups ----
  bf16x8 aQ0[2], aQ1[2];
#pragma unroll
  for (int qg = 0; qg < 2; ++qg) {
    int qrow = qt * 128 + w * 32 + qg * 16 + lc;
    const float* qb = q + ((size_t)b * SQ + qrow) * DMODEL + (size_t)h * DH;
    int d0 = g * 8;
    float __align__(16) x[8], p[8], cs[8], sn[8];
    *(float4*)(x) = *(const float4*)(qb + d0);
    *(float4*)(x + 4) = *(const float4*)(qb + d0 + 4);
    *(float4*)(p) = *(const float4*)(qb + (d0 ^ 16));
    *(float4*)(p + 4) = *(const float4*)(qb + (d0 ^ 16) + 4);
    const float* cb = cosT + qrow * 16 + (g & 1) * 8;
    const float* sb = sinT + qrow * 16 + (g & 1) * 8;
    *(float4*)(cs) = *(const float4*)(cb);
    *(float4*)(cs + 4) = *(const float4*)(cb + 4);
    *(float4*)(sn) = *(const float4*)(sb);
    *(float4*)(sn + 4) = *(const float4*)(sb + 4);
    float sgn = (d0 < 16) ? -1.f : 1.f;
    unsigned short __align__(16) t0[8];
#pragma unroll
    for (int j = 0; j < 8; ++j) t0[j] = f2bf((x[j] * cs[j] + sgn * p[j] * sn[j]) * QSCALE);
    aQ0[qg] = *(bf16x8*)t0;
    *(float4*)(x) = *(const float4*)(qb + 32 + d0);
    *(float4*)(x + 4) = *(const float4*)(qb + 32 + d0 + 4);
#pragma unroll
    for (int j = 0; j < 8; ++j) t0[j] = f2bf(x[j] * QSCALE);
    aQ1[qg] = *(bf16x8*)t0;
  }

  f32x4 oacc[2][4];
  float lrow[2] = {0.f, 0.f};
#pragma unroll
  for (int qg = 0; qg < 2; ++qg)
#pragma unroll
    for (int m = 0; m < 4; ++m) oacc[qg][m] = (f32x4){0.f, 0.f, 0.f, 0.f};

  for (int t = 0; t < SQ / 64; ++t) {
    const unsigned short* Kp = kt + (size_t)t * 4096;
    const unsigned short* Vp = vt + (size_t)t * 4096;
    // K fragments resident (shared by both q-groups)
    bf16x8 kfr[8];
#pragma unroll
    for (int i = 0; i < 8; ++i) kfr[i] = *(const bf16x8*)(Kp + i * 512);

#pragma unroll
    for (int qg = 0; qg < 2; ++qg) {
      // ---- QK^T (S^T), acc-init 0 (shift-0 softmax) ----
      f32x4 sm[4];
#pragma unroll
      for (int m = 0; m < 4; ++m) {
        f32x4 acc = (f32x4){0.f, 0.f, 0.f, 0.f};
        acc = __builtin_amdgcn_mfma_f32_16x16x32_bf16(kfr[2 * m], aQ0[qg], acc, 0, 0, 0);
        acc = __builtin_amdgcn_mfma_f32_16x16x32_bf16(kfr[2 * m + 1], aQ1[qg], acc, 0, 0, 0);
        sm[m] = acc;
      }

      // ---- p = 2^s (bare v_exp_f32; shift cancels in O/l) ----
#pragma unroll
      for (int m = 0; m < 4; ++m)
#pragma unroll
        for (int r2 = 0; r2 < 4; ++r2) sm[m][r2] = fast_exp2(sm[m][r2]);

      // ---- l-sum via VALU reduce (in-lane 16 + cross-group shfl) ----
      {
        f32x4 s01 = sm[0] + sm[1];
        f32x4 s23 = sm[2] + sm[3];
        f32x4 s03 = s01 + s23;
        float rs = (s03[0] + s03[1]) + (s03[2] + s03[3]);
        rs += __shfl_xor(rs, 16);
        rs += __shfl_xor(rs, 32);
        lrow[qg] += rs;
      }

      // ---- P^T -> B-fragments in-register (cvt_pk + permlane swaps) ----
      unsigned wd[4][2];
#pragma unroll
      for (int m = 0; m < 4; ++m) {
        wd[m][0] = cvt_pk_bf16(sm[m][0], sm[m][1]);
        wd[m][1] = cvt_pk_bf16(sm[m][2], sm[m][3]);
      }
      union { unsigned u[4]; bf16x8 v8; } f0, f1;
#pragma unroll
      for (int c = 0; c < 2; ++c) {
        unsigned a = wd[0][c], bq = wd[1][c];
        asm("v_permlane32_swap_b32 %0, %1" : "+v"(a), "+v"(bq));
        asm("v_permlane16_swap_b32 %0, %1" : "+v"(a), "+v"(bq));
        f0.u[c] = a; f0.u[2 + c] = bq;
        unsigned a2 = wd[2][c], b2 = wd[3][c];
        asm("v_permlane32_swap_b32 %0, %1" : "+v"(a2), "+v"(b2));
        asm("v_permlane16_swap_b32 %0, %1" : "+v"(a2), "+v"(b2));
        f1.u[c] = a2; f1.u[2 + c] = b2;
      }

      // ---- PV (O^T); V fragments on-demand (register diet) ----
#pragma unroll
      for (int m = 0; m < 4; ++m) {
        bf16x8 v0 = *(const bf16x8*)(Vp + (2 * m) * 512);
        bf16x8 v1 = *(const bf16x8*)(Vp + (2 * m + 1) * 512);
        oacc[qg][m] = __builtin_amdgcn_mfma_f32_16x16x32_bf16(v0, f0.v8, oacc[qg][m], 0, 0, 0);
        oacc[qg][m] = __builtin_amdgcn_mfma_f32_16x16x32_bf16(v1, f1.v8, oacc[qg][m], 0, 0, 0);
      }
    }
  }

  // ---- register K/V token + final normalize + store ----
#pragma unroll
  for (int qg = 0; qg < 2; ++qg) {
    float part = 0.f;
    const float* kb = kreg + (size_t)h * DH + 32 + g * 8;
#pragma unroll
    for (int j = 0; j < 8; ++j) part += bf2f((unsigned short)aQ1[qg][j]) * kb[j];
    part += __shfl_xor(part, 16);
    part += __shfl_xor(part, 32);
    float pr = fast_exp2(part);
    float lfin = lrow[qg] + pr;
    float inv = 1.f / lfin;
    int qrow = qt * 128 + w * 32 + qg * 16 + lc;
    float* ob = out + ((size_t)b * SQ + qrow) * DMODEL + (size_t)h * DH;
#pragma unroll
    for (int m = 0; m < 4; ++m) {
      float4 vv = *(const float4*)(vreg + (size_t)h * DH + m * 16 + g * 4);
      f32x4 o = oacc[qg][m];
      float4 st;
      st.x = (o[0] + pr * vv.x) * inv;
      st.y = (o[1] + pr * vv.y) * inv;
      st.z = (o[2] + pr * vv.z) * inv;
      st.w = (o[3] + pr * vv.w) * inv;
      *(float4*)(ob + m * 16 + g * 4) = st;
    }
  }
}

// ---------------- fallback (no-workspace) ----------------
__global__ __launch_bounds__(256) void attn_fallback(
    const float* __restrict__ q, const float* __restrict__ k, const float* __restrict__ v,
    const float* __restrict__ kreg, const float* __restrict__ vreg,
    float* __restrict__ out) {
  __shared__ __align__(16) unsigned short Klds[64 * 64];
  __shared__ __align__(16) unsigned short Vtlds[64 * 64];
  __shared__ __align__(16) unsigned short Plds[4][16 * 64];
  int bid = blockIdx.x;
  int xcd = bid & 7, jj = bid >> 3;
  int bh = xcd * 8 + (jj >> 5);
  int qt = jj & 31;
  int b = bh >> 4, h = bh & 15;
  int tid = threadIdx.x, w = tid >> 6, l = tid & 63, g = l >> 4, lc = l & 15;
  int qrow = qt * 64 + w * 16 + lc;
  const float* qb = q + ((size_t)b * SQ + qrow) * DMODEL + (size_t)h * DH;
  bf16x8 aQ0, aQ1;
  {
    int d0 = g * 8;
    float __align__(16) x[8], p[8];
    *(float4*)(x) = *(const float4*)(qb + d0);
    *(float4*)(x + 4) = *(const float4*)(qb + d0 + 4);
    *(float4*)(p) = *(const float4*)(qb + (d0 ^ 16));
    *(float4*)(p + 4) = *(const float4*)(qb + (d0 ^ 16) + 4);
    float sgn = (d0 < 16) ? -1.f : 1.f;
    unsigned short __align__(16) t0[8];
#pragma unroll
    for (int j = 0; j < 8; ++j) {
      int fi = (d0 + j) & 15;
      float ang = (float)qrow * exp2f(NEG_FREQ_LOG2 * (float)fi);
      t0[j] = f2bf((x[j] * cosf(ang) + sgn * p[j] * sinf(ang)) * 0.125f);
    }
    aQ0 = *(bf16x8*)t0;
    *(float4*)(x) = *(const float4*)(qb + 32 + d0);
    *(float4*)(x + 4) = *(const float4*)(qb + 32 + d0 + 4);
#pragma unroll
    for (int j = 0; j < 8; ++j) t0[j] = f2bf(x[j] * 0.125f);
    aQ1 = *(bf16x8*)t0;
  }
  f32x4 oacc[4];
#pragma unroll
  for (int n = 0; n < 4; ++n) oacc[n] = (f32x4){0.f, 0.f, 0.f, 0.f};
  float mrow[4] = {-1e30f, -1e30f, -1e30f, -1e30f};
  float lrow[4] = {0.f, 0.f, 0.f, 0.f};
  int sr = tid >> 2, sq = tid & 3;
  unsigned short* Pw = &Plds[w][0];
  for (int t = 0; t < SQ / 64; ++t) {
    int kv0 = t * 64;
    __syncthreads();
    {
      const float* kb2 = k + ((size_t)b * SQ + kv0 + sr) * DMODEL + (size_t)h * DH + sq * 16;
      float __align__(16) x[16];
#pragma unroll
      for (int c = 0; c < 4; ++c) *(float4*)(x + c * 4) = *(const float4*)(kb2 + c * 4);
      if (sq < 2) {
        const float* pb = k + ((size_t)b * SQ + kv0 + sr) * DMODEL + (size_t)h * DH + (sq ^ 1) * 16;
        float __align__(16) p[16];
#pragma unroll
        for (int c = 0; c < 4; ++c) *(float4*)(p + c * 4) = *(const float4*)(pb + c * 4);
        float sgn = sq ? 1.f : -1.f;
        float pos = (float)(kv0 + sr);
#pragma unroll
        for (int j = 0; j < 16; ++j) {
          float ang = pos * exp2f(NEG_FREQ_LOG2 * (float)j);
          x[j] = x[j] * cosf(ang) + sgn * p[j] * sinf(ang);
        }
      }
      unsigned short __align__(16) o[16];
#pragma unroll
      for (int j = 0; j < 16; ++j) o[j] = f2bf(x[j]);
      int i0 = (sr * 64 + sq * 16) ^ ((sr & 7) << 3);
      int i1 = (sr * 64 + sq * 16 + 8) ^ ((sr & 7) << 3);
      *(uint4*)&Klds[i0] = *(uint4*)o;
      *(uint4*)&Klds[i1] = *(uint4*)(o + 8);
      const float* vb = v + ((size_t)b * SQ + kv0 + sr) * DMODEL + (size_t)h * DH + sq * 16;
#pragma unroll
      for (int c = 0; c < 4; ++c) *(float4*)(x + c * 4) = *(const float4*)(vb + c * 4);
#pragma unroll
      for (int j = 0; j < 16; ++j) {
        int d = sq * 16 + j;
        Vtlds[(d * 64 + sr) ^ ((d & 7) << 3)] = f2bf(x[j]);
      }
    }
    __syncthreads();
    f32x4 sacc[4];
#pragma unroll
    for (int n = 0; n < 4; ++n) {
      int row = n * 16 + lc;
      bf16x8 b0 = *(const bf16x8*)&Klds[(row * 64 + g * 8) ^ ((row & 7) << 3)];
      bf16x8 b1 = *(const bf16x8*)&Klds[(row * 64 + 32 + g * 8) ^ ((row & 7) << 3)];
      f32x4 acc = (f32x4){0.f, 0.f, 0.f, 0.f};
      acc = __builtin_amdgcn_mfma_f32_16x16x32_bf16(aQ0, b0, acc, 0, 0, 0);
      acc = __builtin_amdgcn_mfma_f32_16x16x32_bf16(aQ1, b1, acc, 0, 0, 0);
      sacc[n] = acc;
    }
    float rmax[4];
#pragma unroll
    for (int rg = 0; rg < 4; ++rg)
      rmax[rg] = fmaxf(fmaxf(sacc[0][rg], sacc[1][rg]), fmaxf(sacc[2][rg], sacc[3][rg]));
#pragma unroll
    for (int off = 1; off < 16; off <<= 1)
#pragma unroll
      for (int rg = 0; rg < 4; ++rg) rmax[rg] = fmaxf(rmax[rg], __shfl_xor(rmax[rg], off));
    float mn[4], scl[4];
#pragma unroll
    for (int rg = 0; rg < 4; ++rg) {
      mn[rg] = fmaxf(mrow[rg], rmax[rg]);
      scl[rg] = __expf(mrow[rg] - mn[rg]);
      mrow[rg] = mn[rg];
    }
    float rsum[4] = {0.f, 0.f, 0.f, 0.f};
#pragma unroll
    for (int n = 0; n < 4; ++n)
#pragma unroll
      for (int rg = 0; rg < 4; ++rg) {
        float pe = __expf(sacc[n][rg] - mn[rg]);
        sacc[n][rg] = pe;
        rsum[rg] += pe;
      }
#pragma unroll
    for (int off = 1; off < 16; off <<= 1)
#pragma unroll
      for (int rg = 0; rg < 4; ++rg) rsum[rg] += __shfl_xor(rsum[rg], off);
    f32x4 sv;
#pragma unroll
    for (int rg = 0; rg < 4; ++rg) {
      lrow[rg] = lrow[rg] * scl[rg] + rsum[rg];
      sv[rg] = scl[rg];
    }
#pragma unroll
    for (int n = 0; n < 4; ++n) oacc[n] *= sv;
#pragma unroll
    for (int n = 0; n < 4; ++n)
#pragma unroll
      for (int rg = 0; rg < 4; ++rg) {
        int row = g * 4 + rg;
        Pw[(row * 64 + n * 16 + lc) ^ ((row & 7) << 3)] = f2bf(sacc[n][rg]);
      }
    {
      bf16x8 a0 = *(const bf16x8*)&Pw[(lc * 64 + g * 8) ^ ((lc & 7) << 3)];
      bf16x8 a1 = *(const bf16x8*)&Pw[(lc * 64 + 32 + g * 8) ^ ((lc & 7) << 3)];
#pragma unroll
      for (int n = 0; n < 4; ++n) {
        int vrow = n * 16 + lc;
        bf16x8 b0 = *(const bf16x8*)&Vtlds[(vrow * 64 + g * 8) ^ ((vrow & 7) << 3)];
        bf16x8 b1 = *(const bf16x8*)&Vtlds[(vrow * 64 + 32 + g * 8) ^ ((vrow & 7) << 3)];
        oacc[n] = __builtin_amdgcn_mfma_f32_16x16x32_bf16(a0, b0, oacc[n], 0, 0, 0);
        oacc[n] = __builtin_amdgcn_mfma_f32_16x16x32_bf16(a1, b1, oacc[n], 0, 0, 0);
      }
    }
  }
  float part = 0.f;
  {
    const float* kb = kreg + (size_t)h * DH + 32 + g * 8;
#pragma unroll
    for (int j = 0; j < 8; ++j) part += bf2f((unsigned short)aQ1[j]) * kb[j];
    part += __shfl_xor(part, 16);
    part += __shfl_xor(part, 32);
  }
  float vr[4];
#pragma unroll
  for (int n = 0; n < 4; ++n) vr[n] = vreg[(size_t)h * DH + n * 16 + lc];
#pragma unroll
  for (int rg = 0; rg < 4; ++rg) {
    float s_r = __shfl(part, g * 4 + rg);
    float mn2 = fmaxf(mrow[rg], s_r);
    float scl2 = __expf(mrow[rg] - mn2);
    float pr = __expf(s_r - mn2);
    lrow[rg] = lrow[rg] * scl2 + pr;
    float inv = 1.f / lrow[rg];
#pragma unroll
    for (int n = 0; n < 4; ++n) oacc[n][rg] = (oacc[n][rg] * scl2 + pr * vr[n]) * inv;
  }
  float* ob = out + ((size_t)b * SQ + qt * 64 + w * 16) * DMODEL + (size_t)h * DH;
#pragma unroll
  for (int rg = 0; rg < 4; ++rg) {
    int row = g * 4 + rg;
#pragma unroll
    for (int n = 0; n < 4; ++n) ob[(size_t)row * DMODEL + n * 16 + lc] = oacc[n][rg];
  }
}

extern "C" void kernel_launch(void* const* d_in, const int* in_sizes, int n_in,
                              void* d_out, int out_size, void* d_ws, size_t ws_size,
                              hipStream_t stream) {
  const float* q = (const float*)d_in[0];
  const float* k = (const float*)d_in[1];
  const float* v = (const float*)d_in[2];
  const float* kreg = (const float*)d_in[3];
  const float* vreg = (const float*)d_in[4];
  float* out = (float*)d_out;

  size_t elems = (size_t)B_ * H_ * SQ * DH;  // 8388608
  size_t tbl = (size_t)SQ * 16;
  size_t need = elems * 2ull * 2ull + tbl * 2ull * 4ull;
  if (ws_size >= need) {
    unsigned short* kf = (unsigned short*)d_ws;
    unsigned short* vf = kf + elems;
    float* cosT = (float*)(vf + elems);
    float* sinT = cosT + tbl;
    gen_tbl<<<dim3((int)(tbl / 256)), dim3(256), 0, stream>>>(cosT, sinT);
    prep_frag<<<dim3(2048), dim3(256), 0, stream>>>(k, v, kf, vf, cosT, sinT);
    attn16<<<dim3(1024), dim3(256), 0, stream>>>(q, kreg, vreg, kf, vf, cosT, sinT, out);
  } else {
    attn_fallback<<<dim3(2048), dim3(256), 0, stream>>>(q, k, v, kreg, vreg, out);
  }
}

// Round 18
// 116.580 us; speedup vs baseline: 1.1036x; 1.0372x over previous
//
#include <hip/hip_runtime.h>

#define B_ 4
#define H_ 16
#define SQ 2048
#define DH 64
#define DMODEL 1024

typedef __attribute__((ext_vector_type(8))) short bf16x8;
typedef __attribute__((ext_vector_type(4))) float f32x4;

static __device__ __forceinline__ unsigned short f2bf(float f) {
  union { float f; unsigned u; } v; v.f = f;
  unsigned r = v.u + 0x7fffu + ((v.u >> 16) & 1u);
  return (unsigned short)(r >> 16);
}
static __device__ __forceinline__ float bf2f(unsigned short u) {
  union { unsigned u; float f; } v; v.u = ((unsigned)u) << 16;
  return v.f;
}
static __device__ __forceinline__ unsigned cvt_pk_bf16(float lo, float hi) {
  unsigned r;
  asm("v_cvt_pk_bf16_f32 %0, %1, %2" : "=v"(r) : "v"(lo), "v"(hi));
  return r;
}
// bare v_exp_f32: args are bounded (|x| <~ 20), skip libm's range fixups
static __device__ __forceinline__ float fast_exp2(float x) {
  float r;
  asm("v_exp_f32 %0, %1" : "=v"(r) : "v"(x));
  return r;
}

// -log2(10000)/16
#define NEG_FREQ_LOG2 (-0.8304820237218405f)
#define QSCALE (0.125f * 1.44269504088896f)  // 1/sqrt(64) * log2(e)

// sin/cos tables: [s][j] for s in [0,2048), j in [0,16)
__global__ void gen_tbl(float* __restrict__ cosT, float* __restrict__ sinT) {
  int t = blockIdx.x * 256 + threadIdx.x;
  int s = t >> 4, j = t & 15;
  float ang = (float)s * exp2f(NEG_FREQ_LOG2 * (float)j);
  cosT[t] = cosf(ang);
  sinT[t] = sinf(ang);
}

// Fragment-major prep: for each (bh, t) 64-key tile write
//   K:  elem((m*2+c)*64 + l)*8 + j  = K_roped[key = m*16+(l&15)][d = c*32+(l>>4)*8+j]
//   V^T: same formula              = V[key = c*32+(l>>4)*8+j][d = m*16+(l&15)]
__global__ __launch_bounds__(256) void prep_frag(
    const float* __restrict__ k, const float* __restrict__ v,
    unsigned short* __restrict__ kf, unsigned short* __restrict__ vf,
    const float* __restrict__ cosT, const float* __restrict__ sinT) {
  __shared__ float T[64][68];
  int bid = blockIdx.x;          // bh*32 + t
  int bh = bid >> 5;
  int b = bh >> 4, h = bh & 15;
  int tid = threadIdx.x;
  int sr = tid >> 2, sq = tid & 3;
  int s = (bid & 31) * 64 + sr;
  size_t srcb = ((size_t)b * SQ + s) * DMODEL + (size_t)h * DH + sq * 16;
  size_t obase = (size_t)bid * 4096;

  // ---- K stage (RoPE'd, f32) ----
  {
    float __align__(16) x[16];
#pragma unroll
    for (int c = 0; c < 4; ++c) *(float4*)(x + c * 4) = *(const float4*)(k + srcb + c * 4);
    if (sq < 2) {
      float __align__(16) p[16], cs[16], sn[16];
      const float* pb = k + srcb + (sq ? -16 : 16);
#pragma unroll
      for (int c = 0; c < 4; ++c) *(float4*)(p + c * 4) = *(const float4*)(pb + c * 4);
#pragma unroll
      for (int c = 0; c < 4; ++c) *(float4*)(cs + c * 4) = *(const float4*)(cosT + s * 16 + c * 4);
#pragma unroll
      for (int c = 0; c < 4; ++c) *(float4*)(sn + c * 4) = *(const float4*)(sinT + s * 16 + c * 4);
      float sgn = sq ? 1.f : -1.f;
#pragma unroll
      for (int j = 0; j < 16; ++j) x[j] = x[j] * cs[j] + sgn * p[j] * sn[j];
    }
#pragma unroll
    for (int c = 0; c < 4; ++c) *(float4*)&T[sr][sq * 16 + c * 4] = *(float4*)(x + c * 4);
  }
  __syncthreads();
  // ---- K readout (fragment-major) ----
#pragma unroll
  for (int r = 0; r < 2; ++r) {
    int slot = tid + r * 256;
    int m = slot >> 7, c = (slot >> 6) & 1, l = slot & 63;
    int row = m * 16 + (l & 15), d0 = c * 32 + ((l >> 4) & 3) * 8;
    float4 a = *(float4*)&T[row][d0];
    float4 b2 = *(float4*)&T[row][d0 + 4];
    unsigned short __align__(16) o[8];
    o[0] = f2bf(a.x); o[1] = f2bf(a.y); o[2] = f2bf(a.z); o[3] = f2bf(a.w);
    o[4] = f2bf(b2.x); o[5] = f2bf(b2.y); o[6] = f2bf(b2.z); o[7] = f2bf(b2.w);
    *(uint4*)(kf + obase + slot * 8) = *(uint4*)o;
  }
  __syncthreads();
  // ---- V stage (raw f32) ----
  {
    float __align__(16) x[16];
#pragma unroll
    for (int c = 0; c < 4; ++c) *(float4*)(x + c * 4) = *(const float4*)(v + srcb + c * 4);
#pragma unroll
    for (int c = 0; c < 4; ++c) *(float4*)&T[sr][sq * 16 + c * 4] = *(float4*)(x + c * 4);
  }
  __syncthreads();
  // ---- V^T readout (fragment-major) ----
#pragma unroll
  for (int r = 0; r < 2; ++r) {
    int slot = tid + r * 256;
    int m = slot >> 7, c = (slot >> 6) & 1, l = slot & 63;
    int d = m * 16 + (l & 15), key0 = c * 32 + ((l >> 4) & 3) * 8;
    unsigned short __align__(16) o[8];
#pragma unroll
    for (int j = 0; j < 8; ++j) o[j] = f2bf(T[key0 + j][d]);
    *(uint4*)(vf + obase + slot * 8) = *(uint4*)o;
  }
}

// Flash attention, LDS-free streaming, qg=2 (wave = 32 q-rows), grid 1024.
// Best measured variant (round 15): K frags resident (shared by both qg),
// V frags on-demand, constant-shift softmax with bare v_exp_f32, l-sum via
// ones-MFMA, P redistributed in-register via cvt_pk + permlane swaps.
__global__ __launch_bounds__(256) void attn14(
    const float* __restrict__ q, const float* __restrict__ kreg,
    const float* __restrict__ vreg,
    const unsigned short* __restrict__ kf, const unsigned short* __restrict__ vf,
    const float* __restrict__ cosT, const float* __restrict__ sinT,
    float* __restrict__ out) {
  int bid = blockIdx.x;  // 1024 = 8 xcd x (8 bh x 16 qt)
  int xcd = bid & 7, jj = bid >> 3;
  int bh = xcd * 8 + (jj >> 4);
  int qt = jj & 15;
  int b = bh >> 4, h = bh & 15;
  int tid = threadIdx.x, w = tid >> 6, l = tid & 63, g = l >> 4, lc = l & 15;

  const unsigned short* kt = kf + (size_t)bh * 32 * 4096 + l * 8;
  const unsigned short* vt = vf + (size_t)bh * 32 * 4096 + l * 8;

  // ---- Q fragments (RoPE + QSCALE), 2 q-groups ----
  bf16x8 aQ0[2], aQ1[2];
#pragma unroll
  for (int qg = 0; qg < 2; ++qg) {
    int qrow = qt * 128 + w * 32 + qg * 16 + lc;
    const float* qb = q + ((size_t)b * SQ + qrow) * DMODEL + (size_t)h * DH;
    int d0 = g * 8;
    float __align__(16) x[8], p[8], cs[8], sn[8];
    *(float4*)(x) = *(const float4*)(qb + d0);
    *(float4*)(x + 4) = *(const float4*)(qb + d0 + 4);
    *(float4*)(p) = *(const float4*)(qb + (d0 ^ 16));
    *(float4*)(p + 4) = *(const float4*)(qb + (d0 ^ 16) + 4);
    const float* cb = cosT + qrow * 16 + (g & 1) * 8;
    const float* sb = sinT + qrow * 16 + (g & 1) * 8;
    *(float4*)(cs) = *(const float4*)(cb);
    *(float4*)(cs + 4) = *(const float4*)(cb + 4);
    *(float4*)(sn) = *(const float4*)(sb);
    *(float4*)(sn + 4) = *(const float4*)(sb + 4);
    float sgn = (d0 < 16) ? -1.f : 1.f;
    unsigned short __align__(16) t0[8];
#pragma unroll
    for (int j = 0; j < 8; ++j) t0[j] = f2bf((x[j] * cs[j] + sgn * p[j] * sn[j]) * QSCALE);
    aQ0[qg] = *(bf16x8*)t0;
    *(float4*)(x) = *(const float4*)(qb + 32 + d0);
    *(float4*)(x + 4) = *(const float4*)(qb + 32 + d0 + 4);
#pragma unroll
    for (int j = 0; j < 8; ++j) t0[j] = f2bf(x[j] * QSCALE);
    aQ1[qg] = *(bf16x8*)t0;
  }

  f32x4 oacc[2][4];
  f32x4 lacc[2];
#pragma unroll
  for (int qg = 0; qg < 2; ++qg) {
#pragma unroll
    for (int m = 0; m < 4; ++m) oacc[qg][m] = (f32x4){0.f, 0.f, 0.f, 0.f};
    lacc[qg] = (f32x4){0.f, 0.f, 0.f, 0.f};
  }
  // ones A-fragment (bf16 1.0 = 0x3F80) for l-sum MFMA
  union { unsigned u[4]; bf16x8 v8; } onesf;
#pragma unroll
  for (int i = 0; i < 4; ++i) onesf.u[i] = 0x3F803F80u;

  for (int t = 0; t < SQ / 64; ++t) {
    const unsigned short* Kp = kt + (size_t)t * 4096;
    const unsigned short* Vp = vt + (size_t)t * 4096;
    // K fragments resident (shared by both q-groups)
    bf16x8 kfr[8];
#pragma unroll
    for (int i = 0; i < 8; ++i) kfr[i] = *(const bf16x8*)(Kp + i * 512);

#pragma unroll
    for (int qg = 0; qg < 2; ++qg) {
      // ---- QK^T (S^T), acc-init 0 (shift-0 softmax) ----
      f32x4 sm[4];
#pragma unroll
      for (int m = 0; m < 4; ++m) {
        f32x4 acc = (f32x4){0.f, 0.f, 0.f, 0.f};
        acc = __builtin_amdgcn_mfma_f32_16x16x32_bf16(kfr[2 * m], aQ0[qg], acc, 0, 0, 0);
        acc = __builtin_amdgcn_mfma_f32_16x16x32_bf16(kfr[2 * m + 1], aQ1[qg], acc, 0, 0, 0);
        sm[m] = acc;
      }

      // ---- p = 2^s (bare v_exp_f32; shift cancels in O/l) ----
#pragma unroll
      for (int m = 0; m < 4; ++m)
#pragma unroll
        for (int r2 = 0; r2 < 4; ++r2) sm[m][r2] = fast_exp2(sm[m][r2]);

      // ---- P^T -> B-fragments in-register (cvt_pk + permlane swaps) ----
      unsigned wd[4][2];
#pragma unroll
      for (int m = 0; m < 4; ++m) {
        wd[m][0] = cvt_pk_bf16(sm[m][0], sm[m][1]);
        wd[m][1] = cvt_pk_bf16(sm[m][2], sm[m][3]);
      }
      union { unsigned u[4]; bf16x8 v8; } f0, f1;
#pragma unroll
      for (int c = 0; c < 2; ++c) {
        unsigned a = wd[0][c], bq = wd[1][c];
        asm("v_permlane32_swap_b32 %0, %1" : "+v"(a), "+v"(bq));
        asm("v_permlane16_swap_b32 %0, %1" : "+v"(a), "+v"(bq));
        f0.u[c] = a; f0.u[2 + c] = bq;
        unsigned a2 = wd[2][c], b2 = wd[3][c];
        asm("v_permlane32_swap_b32 %0, %1" : "+v"(a2), "+v"(b2));
        asm("v_permlane16_swap_b32 %0, %1" : "+v"(a2), "+v"(b2));
        f1.u[c] = a2; f1.u[2 + c] = b2;
      }

      // ---- PV (O^T) + l-sum; V fragments on-demand (register diet) ----
#pragma unroll
      for (int m = 0; m < 4; ++m) {
        bf16x8 v0 = *(const bf16x8*)(Vp + (2 * m) * 512);
        bf16x8 v1 = *(const bf16x8*)(Vp + (2 * m + 1) * 512);
        oacc[qg][m] = __builtin_amdgcn_mfma_f32_16x16x32_bf16(v0, f0.v8, oacc[qg][m], 0, 0, 0);
        oacc[qg][m] = __builtin_amdgcn_mfma_f32_16x16x32_bf16(v1, f1.v8, oacc[qg][m], 0, 0, 0);
      }
      lacc[qg] = __builtin_amdgcn_mfma_f32_16x16x32_bf16(onesf.v8, f0.v8, lacc[qg], 0, 0, 0);
      lacc[qg] = __builtin_amdgcn_mfma_f32_16x16x32_bf16(onesf.v8, f1.v8, lacc[qg], 0, 0, 0);
    }
  }

  // ---- register K/V token + final normalize + store ----
#pragma unroll
  for (int qg = 0; qg < 2; ++qg) {
    float part = 0.f;
    const float* kb = kreg + (size_t)h * DH + 32 + g * 8;
#pragma unroll
    for (int j = 0; j < 8; ++j) part += bf2f((unsigned short)aQ1[qg][j]) * kb[j];
    part += __shfl_xor(part, 16);
    part += __shfl_xor(part, 32);
    float pr = fast_exp2(part);
    float lfin = lacc[qg][0] + pr;
    float inv = 1.f / lfin;
    int qrow = qt * 128 + w * 32 + qg * 16 + lc;
    float* ob = out + ((size_t)b * SQ + qrow) * DMODEL + (size_t)h * DH;
#pragma unroll
    for (int m = 0; m < 4; ++m) {
      float4 vv = *(const float4*)(vreg + (size_t)h * DH + m * 16 + g * 4);
      f32x4 o = oacc[qg][m];
      float4 st;
      st.x = (o[0] + pr * vv.x) * inv;
      st.y = (o[1] + pr * vv.y) * inv;
      st.z = (o[2] + pr * vv.z) * inv;
      st.w = (o[3] + pr * vv.w) * inv;
      *(float4*)(ob + m * 16 + g * 4) = st;
    }
  }
}

// ---------------- fallback (no-workspace) ----------------
__global__ __launch_bounds__(256) void attn_fallback(
    const float* __restrict__ q, const float* __restrict__ k, const float* __restrict__ v,
    const float* __restrict__ kreg, const float* __restrict__ vreg,
    float* __restrict__ out) {
  __shared__ __align__(16) unsigned short Klds[64 * 64];
  __shared__ __align__(16) unsigned short Vtlds[64 * 64];
  __shared__ __align__(16) unsigned short Plds[4][16 * 64];
  int bid = blockIdx.x;
  int xcd = bid & 7, jj = bid >> 3;
  int bh = xcd * 8 + (jj >> 5);
  int qt = jj & 31;
  int b = bh >> 4, h = bh & 15;
  int tid = threadIdx.x, w = tid >> 6, l = tid & 63, g = l >> 4, lc = l & 15;
  int qrow = qt * 64 + w * 16 + lc;
  const float* qb = q + ((size_t)b * SQ + qrow) * DMODEL + (size_t)h * DH;
  bf16x8 aQ0, aQ1;
  {
    int d0 = g * 8;
    float __align__(16) x[8], p[8];
    *(float4*)(x) = *(const float4*)(qb + d0);
    *(float4*)(x + 4) = *(const float4*)(qb + d0 + 4);
    *(float4*)(p) = *(const float4*)(qb + (d0 ^ 16));
    *(float4*)(p + 4) = *(const float4*)(qb + (d0 ^ 16) + 4);
    float sgn = (d0 < 16) ? -1.f : 1.f;
    unsigned short __align__(16) t0[8];
#pragma unroll
    for (int j = 0; j < 8; ++j) {
      int fi = (d0 + j) & 15;
      float ang = (float)qrow * exp2f(NEG_FREQ_LOG2 * (float)fi);
      t0[j] = f2bf((x[j] * cosf(ang) + sgn * p[j] * sinf(ang)) * 0.125f);
    }
    aQ0 = *(bf16x8*)t0;
    *(float4*)(x) = *(const float4*)(qb + 32 + d0);
    *(float4*)(x + 4) = *(const float4*)(qb + 32 + d0 + 4);
#pragma unroll
    for (int j = 0; j < 8; ++j) t0[j] = f2bf(x[j] * 0.125f);
    aQ1 = *(bf16x8*)t0;
  }
  f32x4 oacc[4];
#pragma unroll
  for (int n = 0; n < 4; ++n) oacc[n] = (f32x4){0.f, 0.f, 0.f, 0.f};
  float mrow[4] = {-1e30f, -1e30f, -1e30f, -1e30f};
  float lrow[4] = {0.f, 0.f, 0.f, 0.f};
  int sr = tid >> 2, sq = tid & 3;
  unsigned short* Pw = &Plds[w][0];
  for (int t = 0; t < SQ / 64; ++t) {
    int kv0 = t * 64;
    __syncthreads();
    {
      const float* kb2 = k + ((size_t)b * SQ + kv0 + sr) * DMODEL + (size_t)h * DH + sq * 16;
      float __align__(16) x[16];
#pragma unroll
      for (int c = 0; c < 4; ++c) *(float4*)(x + c * 4) = *(const float4*)(kb2 + c * 4);
      if (sq < 2) {
        const float* pb = k + ((size_t)b * SQ + kv0 + sr) * DMODEL + (size_t)h * DH + (sq ^ 1) * 16;
        float __align__(16) p[16];
#pragma unroll
        for (int c = 0; c < 4; ++c) *(float4*)(p + c * 4) = *(const float4*)(pb + c * 4);
        float sgn = sq ? 1.f : -1.f;
        float pos = (float)(kv0 + sr);
#pragma unroll
        for (int j = 0; j < 16; ++j) {
          float ang = pos * exp2f(NEG_FREQ_LOG2 * (float)j);
          x[j] = x[j] * cosf(ang) + sgn * p[j] * sinf(ang);
        }
      }
      unsigned short __align__(16) o[16];
#pragma unroll
      for (int j = 0; j < 16; ++j) o[j] = f2bf(x[j]);
      int i0 = (sr * 64 + sq * 16) ^ ((sr & 7) << 3);
      int i1 = (sr * 64 + sq * 16 + 8) ^ ((sr & 7) << 3);
      *(uint4*)&Klds[i0] = *(uint4*)o;
      *(uint4*)&Klds[i1] = *(uint4*)(o + 8);
      const float* vb = v + ((size_t)b * SQ + kv0 + sr) * DMODEL + (size_t)h * DH + sq * 16;
#pragma unroll
      for (int c = 0; c < 4; ++c) *(float4*)(x + c * 4) = *(const float4*)(vb + c * 4);
#pragma unroll
      for (int j = 0; j < 16; ++j) {
        int d = sq * 16 + j;
        Vtlds[(d * 64 + sr) ^ ((d & 7) << 3)] = f2bf(x[j]);
      }
    }
    __syncthreads();
    f32x4 sacc[4];
#pragma unroll
    for (int n = 0; n < 4; ++n) {
      int row = n * 16 + lc;
      bf16x8 b0 = *(const bf16x8*)&Klds[(row * 64 + g * 8) ^ ((row & 7) << 3)];
      bf16x8 b1 = *(const bf16x8*)&Klds[(row * 64 + 32 + g * 8) ^ ((row & 7) << 3)];
      f32x4 acc = (f32x4){0.f, 0.f, 0.f, 0.f};
      acc = __builtin_amdgcn_mfma_f32_16x16x32_bf16(aQ0, b0, acc, 0, 0, 0);
      acc = __builtin_amdgcn_mfma_f32_16x16x32_bf16(aQ1, b1, acc, 0, 0, 0);
      sacc[n] = acc;
    }
    float rmax[4];
#pragma unroll
    for (int rg = 0; rg < 4; ++rg)
      rmax[rg] = fmaxf(fmaxf(sacc[0][rg], sacc[1][rg]), fmaxf(sacc[2][rg], sacc[3][rg]));
#pragma unroll
    for (int off = 1; off < 16; off <<= 1)
#pragma unroll
      for (int rg = 0; rg < 4; ++rg) rmax[rg] = fmaxf(rmax[rg], __shfl_xor(rmax[rg], off));
    float mn[4], scl[4];
#pragma unroll
    for (int rg = 0; rg < 4; ++rg) {
      mn[rg] = fmaxf(mrow[rg], rmax[rg]);
      scl[rg] = __expf(mrow[rg] - mn[rg]);
      mrow[rg] = mn[rg];
    }
    float rsum[4] = {0.f, 0.f, 0.f, 0.f};
#pragma unroll
    for (int n = 0; n < 4; ++n)
#pragma unroll
      for (int rg = 0; rg < 4; ++rg) {
        float pe = __expf(sacc[n][rg] - mn[rg]);
        sacc[n][rg] = pe;
        rsum[rg] += pe;
      }
#pragma unroll
    for (int off = 1; off < 16; off <<= 1)
#pragma unroll
      for (int rg = 0; rg < 4; ++rg) rsum[rg] += __shfl_xor(rsum[rg], off);
    f32x4 sv;
#pragma unroll
    for (int rg = 0; rg < 4; ++rg) {
      lrow[rg] = lrow[rg] * scl[rg] + rsum[rg];
      sv[rg] = scl[rg];
    }
#pragma unroll
    for (int n = 0; n < 4; ++n) oacc[n] *= sv;
#pragma unroll
    for (int n = 0; n < 4; ++n)
#pragma unroll
      for (int rg = 0; rg < 4; ++rg) {
        int row = g * 4 + rg;
        Pw[(row * 64 + n * 16 + lc) ^ ((row & 7) << 3)] = f2bf(sacc[n][rg]);
      }
    {
      bf16x8 a0 = *(const bf16x8*)&Pw[(lc * 64 + g * 8) ^ ((lc & 7) << 3)];
      bf16x8 a1 = *(const bf16x8*)&Pw[(lc * 64 + 32 + g * 8) ^ ((lc & 7) << 3)];
#pragma unroll
      for (int n = 0; n < 4; ++n) {
        int vrow = n * 16 + lc;
        bf16x8 b0 = *(const bf16x8*)&Vtlds[(vrow * 64 + g * 8) ^ ((vrow & 7) << 3)];
        bf16x8 b1 = *(const bf16x8*)&Vtlds[(vrow * 64 + 32 + g * 8) ^ ((vrow & 7) << 3)];
        oacc[n] = __builtin_amdgcn_mfma_f32_16x16x32_bf16(a0, b0, oacc[n], 0, 0, 0);
        oacc[n] = __builtin_amdgcn_mfma_f32_16x16x32_bf16(a1, b1, oacc[n], 0, 0, 0);
      }
    }
  }
  float part = 0.f;
  {
    const float* kb = kreg + (size_t)h * DH + 32 + g * 8;
#pragma unroll
    for (int j = 0; j < 8; ++j) part += bf2f((unsigned short)aQ1[j]) * kb[j];
    part += __shfl_xor(part, 16);
    part += __shfl_xor(part, 32);
  }
  float vr[4];
#pragma unroll
  for (int n = 0; n < 4; ++n) vr[n] = vreg[(size_t)h * DH + n * 16 + lc];
#pragma unroll
  for (int rg = 0; rg < 4; ++rg) {
    float s_r = __shfl(part, g * 4 + rg);
    float mn2 = fmaxf(mrow[rg], s_r);
    float scl2 = __expf(mrow[rg] - mn2);
    float pr = __expf(s_r - mn2);
    lrow[rg] = lrow[rg] * scl2 + pr;
    float inv = 1.f / lrow[rg];
#pragma unroll
    for (int n = 0; n < 4; ++n) oacc[n][rg] = (oacc[n][rg] * scl2 + pr * vr[n]) * inv;
  }
  float* ob = out + ((size_t)b * SQ + qt * 64 + w * 16) * DMODEL + (size_t)h * DH;
#pragma unroll
  for (int rg = 0; rg < 4; ++rg) {
    int row = g * 4 + rg;
#pragma unroll
    for (int n = 0; n < 4; ++n) ob[(size_t)row * DMODEL + n * 16 + lc] = oacc[n][rg];
  }
}

extern "C" void kernel_launch(void* const* d_in, const int* in_sizes, int n_in,
                              void* d_out, int out_size, void* d_ws, size_t ws_size,
                              hipStream_t stream) {
  const float* q = (const float*)d_in[0];
  const float* k = (const float*)d_in[1];
  const float* v = (const float*)d_in[2];
  const float* kreg = (const float*)d_in[3];
  const float* vreg = (const float*)d_in[4];
  float* out = (float*)d_out;

  size_t elems = (size_t)B_ * H_ * SQ * DH;  // 8388608
  size_t tbl = (size_t)SQ * 16;
  size_t need = elems * 2ull * 2ull + tbl * 2ull * 4ull;
  if (ws_size >= need) {
    unsigned short* kf = (unsigned short*)d_ws;
    unsigned short* vf = kf + elems;
    float* cosT = (float*)(vf + elems);
    float* sinT = cosT + tbl;
    gen_tbl<<<dim3((int)(tbl / 256)), dim3(256), 0, stream>>>(cosT, sinT);
    prep_frag<<<dim3(2048), dim3(256), 0, stream>>>(k, v, kf, vf, cosT, sinT);
    attn14<<<dim3(1024), dim3(256), 0, stream>>>(q, kreg, vreg, kf, vf, cosT, sinT, out);
  } else {
    attn_fallback<<<dim3(2048), dim3(256), 0, stream>>>(q, k, v, kreg, vreg, out);
  }
}